// Round 5
// baseline (63262.292 us; speedup 1.0000x reference)
//
#include <hip/hip_runtime.h>
#include <cstdint>

#define LSEQ 256
#define NBLK 256
#define BN_INV 0.99999500003750f
#define DYN_LDS_BYTES 134784   // 33696 floats

typedef float v4f __attribute__((ext_vector_type(4)));

// LDS layout (floats)
#define O_XL   0        // 8320  staging 32x260
#define O_TG   8320     // 544   transpose / reduce scratch
#define O_SBC  8864     // 128   c-state
#define O_SBZ  8992     // 128   zoneout z-prev state
#define O_W4   9120     // 16384 main weight slice, v4-k layout
#define O_EXT  25504    // role extras: WF(2048)+Wd4(2048) | Wp4(8192) | ATT
#define O_G    25504    // ATT: 3968
#define O_AWL  29472    // ATT: 288
#define O_PL   29760    // ATT: 256
#define O_DEC  30016    // ATT: 128
#define O_RED  30144    // ATT: 64

struct Args {
  const float *enc_z, *ys;
  const int* ilens;
  const float *W_enc, *b_enc, *W_dec, *loc_kernel, *W_att, *g_w, *g_b;
  const float *Wp0, *bp0, *Wp1, *bp1;
  const float *Wih0, *Whh0, *bih0, *bhh0, *Wih1, *Whh1, *bih1, *bhh1;
  const float *Wf, *bf, *Wq, *bq;
  const float *pk0,*pb0,*bg0,*bb0,*pk1,*pb1,*bg1,*bb1,*pk2,*pb2,*bg2,*bb2;
  float *enc_proj, *pre_tmp, *pre_all, *G, *dec, *att_c;
  float *z0, *z1, *gpre0, *gpre1, *biasP0, *biasP1;
  float *before_t, *h0, *h1, *Wt0, *Wt1, *Wt2, *s0, *t0s, *s1, *t1s, *s2, *t2s;
  int* bar;
  float *out_after, *out_before, *out_logits, *out_aws;
};

__device__ __forceinline__ float sigf(float x){ return 1.0f/(1.0f+expf(-x)); }
__device__ __forceinline__ float hsum(const v4f& v){ return v.x+v.y+v.z+v.w; }

// ---- agent(device)-scope access helpers: sc1 = bypass per-XCD L2, CACHED in LLC ----
__device__ __forceinline__ float ldc(const float* p){
  float v;
  asm volatile("global_load_dword %0, %1, off sc1\n\ts_waitcnt vmcnt(0)"
               : "=v"(v) : "v"(p) : "memory");
  return v;
}
__device__ __forceinline__ v4f ldc4(const float* p){
  v4f v;
  asm volatile("global_load_dwordx4 %0, %1, off sc1\n\ts_waitcnt vmcnt(0)"
               : "=v"(v) : "v"(p) : "memory");
  return v;
}
__device__ __forceinline__ v4f ldc4_nw(const float* p){
  v4f v;
  asm volatile("global_load_dwordx4 %0, %1, off sc1"
               : "=v"(v) : "v"(p) : "memory");
  return v;
}
__device__ __forceinline__ void waitvm2(v4f& a, v4f& b){
  asm volatile("s_waitcnt vmcnt(0)" : "+v"(a), "+v"(b) :: "memory");
}
__device__ __forceinline__ void stc(float* p, float v){
  asm volatile("global_store_dword %0, %1, off sc1" :: "v"(p), "v"(v) : "memory");
}
__device__ __forceinline__ int ldci(const int* p){
  int v;
  asm volatile("global_load_dword %0, %1, off sc1\n\ts_waitcnt vmcnt(0)"
               : "=v"(v) : "v"(p) : "memory");
  return v;
}
__device__ __forceinline__ void stci(int* p, int v){
  asm volatile("global_store_dword %0, %1, off sc1" :: "v"(p), "v"(v) : "memory");
}
__device__ __forceinline__ void waitvm_all(){
  asm volatile("s_waitcnt vmcnt(0)" ::: "memory");
}

// ---- register-prefetch staging: issue 8x dwordx4 (one 32x256 chunk) into q0..q7 ----
#define PFI(base,koff) do{ const float* _b=(const float*)(base)+(koff); \
  int _r=tid>>6; int _c=(tid&63)*4; \
  q0=ldc4_nw(_b+(size_t)(_r    )*512+_c); q1=ldc4_nw(_b+(size_t)(_r+ 4)*512+_c); \
  q2=ldc4_nw(_b+(size_t)(_r+ 8)*512+_c); q3=ldc4_nw(_b+(size_t)(_r+12)*512+_c); \
  q4=ldc4_nw(_b+(size_t)(_r+16)*512+_c); q5=ldc4_nw(_b+(size_t)(_r+20)*512+_c); \
  q6=ldc4_nw(_b+(size_t)(_r+24)*512+_c); q7=ldc4_nw(_b+(size_t)(_r+28)*512+_c); }while(0)

#define PFW(XLP) do{ waitvm_all(); __syncthreads(); \
  float* _x=(XLP)+(tid>>6)*260+(tid&63)*4; \
  *(v4f*)(_x)=q0; *(v4f*)(_x+1040)=q1; *(v4f*)(_x+2080)=q2; *(v4f*)(_x+3120)=q3; \
  *(v4f*)(_x+4160)=q4; *(v4f*)(_x+5200)=q5; *(v4f*)(_x+6240)=q6; *(v4f*)(_x+7280)=q7; \
  __syncthreads(); }while(0)

// ---- grid barrier: per-block arrive lines, leader(42) gathers, 32 release lines ----
__device__ __forceinline__ void gbar(int* bar, int rnd, int blk, int tid){
  waitvm_all();
  __syncthreads();
  if (tid == 0) stci(bar + blk*16, rnd);
  if (blk == 42){
    waitvm_all();
    int ok;
    do {
      int v = ldci(bar + tid*16);
      ok = __syncthreads_count(v >= rnd);
      if (ok < 256) __builtin_amdgcn_s_sleep(1);
    } while (ok < 256);
    if (tid < 32) stci(bar + 4096 + tid*16, rnd);
    __syncthreads();
  } else {
    if (tid == 0){
      const int* rel = bar + 4096 + (blk>>3)*16;
      while (ldci(rel) < rnd) __builtin_amdgcn_s_sleep(2);
    }
    __syncthreads();
  }
}

// ---------------- init ----------------
__global__ void k_init(Args A){
  int tid0 = blockIdx.x*blockDim.x + threadIdx.x;
  int stride = gridDim.x*blockDim.x;
  for (int i = tid0; i < 31*128; i += stride){
    int k = i >> 7, d = i & 127;
    float s = 0.f;
    for (int c = 0; c < 32; ++c) s += A.W_att[c*128+d]*A.loc_kernel[c*31+k];
    A.G[i] = s;
  }
  for (int i = tid0; i < 2048; i += stride){
    int u = i & 511, g = i >> 9;
    A.biasP0[u*4+g] = A.bih0[i]+A.bhh0[i];
    A.biasP1[u*4+g] = A.bih1[i]+A.bhh1[i];
  }
  for (int i = tid0; i < 16384; i += stride) A.z0[i]=0.f;
  for (int i = tid0; i < 32768; i += stride) A.z1[i]=0.f;
  for (int i = tid0; i < 65536; i += stride) A.gpre0[i]=0.f;
  for (int i = tid0; i < 131072; i += stride) A.gpre1[i]=0.f;
  for (int i = tid0; i < 4096; i += stride) A.dec[i]=0.f;
  for (int i = tid0; i < 4608; i += stride) A.bar[i]=0;
  for (int i = tid0; i < 512; i += stride){
    float s = A.bg0[i]*BN_INV; A.s0[i]=s; A.t0s[i]=s*A.pb0[i]+A.bb0[i];
    float u = A.bg1[i]*BN_INV; A.s1[i]=u; A.t1s[i]=u*A.pb1[i]+A.bb1[i];
  }
  for (int i = tid0; i < 80; i += stride){
    float s = A.bg2[i]*BN_INV; A.s2[i]=s; A.t2s[i]=s*A.pb2[i]+A.bb2[i];
  }
  for (int i = tid0; i < 5*80*512; i += stride){
    int k = i/(80*512); int r = i - k*(80*512); int c = r>>9, n = r&511;
    A.Wt0[i] = A.pk0[(n*80+c)*5+k];
  }
  for (int i = tid0; i < 5*512*512; i += stride){
    int k = i/(512*512); int r = i - k*(512*512); int c = r>>9, n = r&511;
    A.Wt1[i] = A.pk1[(n*512+c)*5+k];
  }
  for (int i = tid0; i < 5*512*80; i += stride){
    int k = i/(512*80); int r = i - k*(512*80); int c = r/80, n = r - c*80;
    A.Wt2[i] = A.pk2[(n*512+c)*5+k];
  }
}

// ---------------- enc_proj ----------------
__global__ void __launch_bounds__(256) k_encproj(Args A){
  __shared__ __align__(16) float As[32][128];
  int m0 = blockIdx.x*32;
  int tid = threadIdx.x;
  int d = tid & 127, half = tid >> 7;
  float acc[16];
  #pragma unroll
  for (int r = 0; r < 16; ++r) acc[r] = 0.f;
  for (int j0 = 0; j0 < 512; j0 += 128){
    for (int i = 0; i < 16; ++i){
      int e = tid + i*256; int r = e >> 7, j = e & 127;
      As[r][j] = A.enc_z[(size_t)(m0+r)*512 + j0 + j];
    }
    __syncthreads();
    for (int j = 0; j < 128; ++j){
      float w = A.W_enc[(size_t)(j0+j)*128 + d];
      #pragma unroll
      for (int r = 0; r < 16; ++r) acc[r] += As[half*16+r][j]*w;
    }
    __syncthreads();
  }
  float be = A.b_enc[d];
  for (int r = 0; r < 16; ++r)
    A.enc_proj[(size_t)(m0+half*16+r)*128 + d] = acc[r] + be;
}

// ---------------- prenet ----------------
__global__ void __launch_bounds__(256) k_pre0(Args A){
  __shared__ float As[32][80];
  int m0 = blockIdx.x*32, tid = threadIdx.x;
  for (int e = tid; e < 2560; e += 256){
    int r = e/80, o = e - r*80;
    int row = m0+r; int l = row & 255, b = row >> 8;
    As[r][o] = (l==0) ? 0.f : A.ys[((size_t)b*256 + (l-1))*80 + o];
  }
  __syncthreads();
  float acc[32];
  #pragma unroll
  for (int r = 0; r < 32; ++r) acc[r] = 0.f;
  for (int o = 0; o < 80; ++o){
    float w = A.Wp0[o*256 + tid];
    #pragma unroll
    for (int r = 0; r < 32; ++r) acc[r] += As[r][o]*w;
  }
  float bb = A.bp0[tid];
  for (int r = 0; r < 32; ++r){
    float v = acc[r]+bb;
    A.pre_tmp[(size_t)(m0+r)*256 + tid] = v>0.f?v:0.f;
  }
}

__global__ void __launch_bounds__(256) k_pre1(Args A){
  __shared__ float As[32][256];
  int m0 = blockIdx.x*32, tid = threadIdx.x;
  for (int e = tid; e < 8192; e += 256){
    int r = e >> 8, j = e & 255;
    As[r][j] = A.pre_tmp[(size_t)(m0+r)*256 + j];
  }
  __syncthreads();
  float acc[32];
  #pragma unroll
  for (int r = 0; r < 32; ++r) acc[r] = 0.f;
  for (int j = 0; j < 256; ++j){
    float w = A.Wp1[j*256 + tid];
    #pragma unroll
    for (int r = 0; r < 32; ++r) acc[r] += As[r][j]*w;
  }
  float bb = A.bp1[tid];
  for (int r = 0; r < 32; ++r){
    float v = acc[r]+bb;
    A.pre_all[(size_t)(m0+r)*256 + tid] = v>0.f?v:0.f;
  }
}

// ---- stage 32 rows x 256 floats into LDS (pitch 260), plain (L2-cached read-only) ----
__device__ __forceinline__ void stage256_plain(const float* base, int rowstride, int koff,
                                               float* Xl, int tid){
  v4f r0,r1,r2,r3,r4,r5,r6,r7;
  #define LDX(i,dst) { int f=tid+((i)<<8); int b=f>>6; int jq=f&63; \
      dst = *(const v4f*)(base + (size_t)b*rowstride + koff + jq*4); }
  LDX(0,r0) LDX(1,r1) LDX(2,r2) LDX(3,r3) LDX(4,r4) LDX(5,r5) LDX(6,r6) LDX(7,r7)
  #undef LDX
  __syncthreads();
  #define STX(i,src) { int f=tid+((i)<<8); int b=f>>6; int jq=f&63; \
      *(v4f*)&Xl[b*260 + jq*4] = src; }
  STX(0,r0) STX(1,r1) STX(2,r2) STX(3,r3) STX(4,r4) STX(5,r5) STX(6,r6) STX(7,r7)
  #undef STX
  __syncthreads();
}

// ---- K=256 chunk gemm: W4 v4-k layout [k/4][16][4]; thread -> cols (tid&7),(tid&7)+8 ----
__device__ __forceinline__ void gemmK256(const float* __restrict__ W4,
                                         const float* __restrict__ Xl,
                                         int tid, v4f& a0, v4f& a1){
  const int q = tid & 7, b = tid >> 3;
  const float* xr = Xl + b*260;
  #pragma unroll 8
  for (int jq = 0; jq < 64; ++jq){
    v4f xv = *(const v4f*)&xr[jq*4];
    v4f w0 = *(const v4f*)&W4[jq*64 + q*4];
    v4f w1 = *(const v4f*)&W4[jq*64 + (q+8)*4];
    a0 += xv*w0; a1 += xv*w1;
  }
}

// ---- out(t): 41 blocks x 2 cols of [Wf|Wq], K=1024 over [z1; att_c], pipelined ----
__device__ __forceinline__ void out_phase(const Args& A, const float* z1b, const float* acb,
                                          int tt, int blk, int tid, float* Xl, float* Tg,
                                          const float* WF){
  int b = tid >> 3, sub = tid & 7;
  float acc0 = 0.f, acc1 = 0.f;
  v4f q0,q1,q2,q3,q4,q5,q6,q7;
  PFI(z1b, 0);
  #pragma unroll
  for (int pass = 0; pass < 4; ++pass){
    PFW(Xl);
    if (pass == 0) PFI(z1b, 256);
    else if (pass == 1) PFI(acb, 0);
    else if (pass == 2) PFI(acb, 256);
    int kbase = pass*256;
    #pragma unroll 4
    for (int i = 0; i < 32; ++i){
      int k = sub + 8*i;
      float x = Xl[b*260 + k];
      acc0 += x*WF[(kbase+k)*2 + 0];
      acc1 += x*WF[(kbase+k)*2 + 1];
    }
  }
  __syncthreads();
  Tg[(b*8+sub)*2+0] = acc0; Tg[(b*8+sub)*2+1] = acc1;
  __syncthreads();
  if (tid < 64){
    int b2 = tid >> 1, e = tid & 1, cg = blk*2 + e;
    float v = (cg < 80) ? A.bf[cg] : A.bq[0];
    for (int s = 0; s < 8; ++s) v += Tg[(b2*8+s)*2 + e];
    if (cg < 80){
      A.out_before[((size_t)b2*256 + tt)*80 + cg] = v;
      A.before_t[((size_t)b2*80 + cg)*256 + tt] = v;
    } else if (cg == 80){
      A.out_logits[(size_t)b2*256 + tt] = v;
    }
  }
}

// ---- gpre1(tp) on GP1 blocks: 32 cols, K=256 over pre(tp) ----
__device__ __forceinline__ void gp1_phase(const Args& A, int tp, int m2, int tid,
                                          float* Xl, const float* Wp4){
  stage256_plain(A.pre_all + (size_t)tp*256, 65536, 0, Xl, tid);
  int q = tid & 7, b = tid >> 3;
  v4f a0={0,0,0,0}, a1={0,0,0,0}, a2={0,0,0,0}, a3={0,0,0,0};
  const float* xr = Xl + b*260;
  #pragma unroll 8
  for (int jq = 0; jq < 64; ++jq){
    v4f xv = *(const v4f*)&xr[jq*4];
    a0 += xv * (*(const v4f*)&Wp4[jq*128 + q*4]);
    a1 += xv * (*(const v4f*)&Wp4[jq*128 + (q+8)*4]);
    a2 += xv * (*(const v4f*)&Wp4[jq*128 + (q+16)*4]);
    a3 += xv * (*(const v4f*)&Wp4[jq*128 + (q+24)*4]);
  }
  float* dst = A.gpre1 + (tp&1)*65536 + b*2048 + m2*32;
  stc(dst + q,      hsum(a0));
  stc(dst + q + 8,  hsum(a1));
  stc(dst + q + 16, hsum(a2));
  stc(dst + q + 24, hsum(a3));
}

// ---------------- the scan: persistent, 3 barriers/step ----------------
__global__ void __launch_bounds__(256, 1) k_scan(Args A){
  extern __shared__ float L[];
  const int blk = blockIdx.x, tid = threadIdx.x;
  float* Xl  = L + O_XL;
  float* Tg  = L + O_TG;
  float* SBc = L + O_SBC;
  float* SBz = L + O_SBZ;
  float* W4  = L + O_W4;
  int rnd = 0;
  const bool isL0  = (blk < 128);
  const bool isGP1 = (blk >= 128 && blk < 192);
  const bool isATT = (blk >= 224);
  #define GBAR() gbar(A.bar, ++rnd, blk, tid)

  // ---- one-time LDS fills ----
  if (isL0){
    for (int idx = tid; idx < 16384; idx += 256){
      int kq = idx >> 6, rem = idx & 63, p = rem >> 2, kl = rem & 3;
      int k = kq*4 + kl;
      int gcol = (p & 3)*512 + blk*4 + (p >> 2);
      W4[idx] = (k < 512) ? A.Wih0[(size_t)k*2048 + gcol]
                          : A.Whh0[(size_t)(k-512)*2048 + gcol];
    }
    if (blk < 41){
      float* WF = L + O_EXT;
      int c0 = blk*2;
      for (int k = tid; k < 1024; k += 256){
        WF[k*2+0] = (c0   < 80) ? A.Wf[(size_t)k*80 + c0]   : A.Wq[k];
        WF[k*2+1] = (c0+1 < 80) ? A.Wf[(size_t)k*80 + c0+1] : A.Wq[k];
      }
    }
    if (blk < 32){
      float* Wd4 = L + O_EXT + 2048;   // [k<512][4 cols]
      for (int i = tid; i < 2048; i += 256){
        int k = i >> 2, c = i & 3;
        Wd4[i] = A.W_dec[(size_t)k*128 + blk*4 + c];
      }
    }
  } else {
    int m = blk - 128;
    for (int idx = tid; idx < 16384; idx += 256){
      int kq = idx >> 6, rem = idx & 63, p = rem >> 2, kl = rem & 3;
      int k = kq*4 + kl;
      int gcol = (p & 3)*512 + m*4 + (p >> 2);
      W4[idx] = (k < 512) ? A.Wih1[(size_t)k*2048 + gcol]
                          : A.Whh1[(size_t)(k-512)*2048 + gcol];
    }
    if (isGP1){
      float* Wp4 = L + O_EXT;
      for (int idx = tid; idx < 8192; idx += 256){
        int kq = idx >> 7, rem = idx & 127, p = rem >> 2, kl = rem & 3;
        int k = kq*4 + kl;
        int gcol = (p & 3)*512 + m*8 + (p >> 2);
        Wp4[idx] = A.Wih0[(size_t)(512+k)*2048 + gcol];
      }
    }
    if (isATT){
      float* Gs  = L + O_G;
      float* awL = L + O_AWL;
      for (int e = tid; e < 3968; e += 256) Gs[e] = A.G[e];
      int b = blk - 224, il = A.ilens[b];
      for (int i = tid; i < 288; i += 256){
        int t = i - 15;
        awL[i] = ((unsigned)t < 256u && t < il) ? 1.0f/(float)il : 0.0f;
      }
    }
  }
  if (tid < 128){ SBc[tid] = 0.f; SBz[tid] = 0.f; }
  __syncthreads();

  // ---- P0: gpre1 for t=0 ----
  if (isGP1) gp1_phase(A, 0, blk-128, tid, Xl, L + O_EXT);
  GBAR();

  for (int t = 0; t < LSEQ; ++t){
    const int par = t & 1;

    // ========== P1: attention (ATT) + out(t-1) (blk<41) ==========
    if (isATT){
      float* Gs  = L + O_G;
      float* awL = L + O_AWL;
      float* pL  = L + O_PL;
      float* decs= L + O_DEC;
      float* red = L + O_RED;
      int b = blk - 224, il = A.ilens[b];
      float gb = A.g_b[0];
      if (tid < 32) *(v4f*)&decs[tid*4] = ldc4(A.dec + b*128 + tid*4);
      __syncthreads();
      int dg = tid & 7, ttg = tid >> 3;
      int d0 = dg*16, tt0 = ttg*8;
      float ebuf[8];
      #pragma unroll
      for (int h = 0; h < 2; ++h){
        int ttb = tt0 + h*4;
        float aw[34];
        #pragma unroll
        for (int i = 0; i < 34; ++i) aw[i] = awL[ttb + i];
        v4f acc[4][4];
        #pragma unroll
        for (int i = 0; i < 4; ++i)
          #pragma unroll
          for (int r = 0; r < 4; ++r) acc[i][r] = (v4f){0.f,0.f,0.f,0.f};
        #pragma unroll
        for (int k = 0; k < 31; ++k){
          const float* gp = &Gs[k*128 + d0];
          v4f g0 = *(const v4f*)&gp[0],  g1 = *(const v4f*)&gp[4];
          v4f g2 = *(const v4f*)&gp[8],  g3 = *(const v4f*)&gp[12];
          #pragma unroll
          for (int i = 0; i < 4; ++i){
            float a = aw[i + k];
            acc[i][0] += g0*a; acc[i][1] += g1*a; acc[i][2] += g2*a; acc[i][3] += g3*a;
          }
        }
        #pragma unroll
        for (int i = 0; i < 4; ++i){
          int tt = ttb + i;
          const float* ep = A.enc_proj + ((size_t)b*256 + tt)*128 + d0;
          float s = 0.f;
          #pragma unroll
          for (int r = 0; r < 4; ++r){
            v4f v = acc[i][r] + *(const v4f*)&ep[r*4] + *(const v4f*)&decs[d0 + r*4];
            v4f gv = *(const v4f*)&A.g_w[d0 + r*4];
            s += tanhf(v.x)*gv.x + tanhf(v.y)*gv.y + tanhf(v.z)*gv.z + tanhf(v.w)*gv.w;
          }
          s += __shfl_xor(s,1); s += __shfl_xor(s,2); s += __shfl_xor(s,4);
          ebuf[h*4+i] = s;
        }
      }
      if (dg == 0){
        #pragma unroll
        for (int i = 0; i < 8; ++i){
          int tt = tt0 + i;
          float e = ebuf[i] + gb;
          pL[tt] = (tt < il) ? expf(2.0f*e) : 0.0f;
        }
      }
      __syncthreads();
      float pv = pL[tid];
      {
        float v = pv;
        v += __shfl_xor(v,1); v += __shfl_xor(v,2); v += __shfl_xor(v,4);
        v += __shfl_xor(v,8); v += __shfl_xor(v,16); v += __shfl_xor(v,32);
        if ((tid & 63) == 0) red[tid>>6] = v;
      }
      __syncthreads();
      float inv = 1.0f/(red[0]+red[1]+red[2]+red[3]);
      float awn = pv*inv;
      stc(A.out_aws + ((size_t)b*256 + t)*256 + tid, awn);
      awL[15 + tid] = awn;
      // att_c
      float a0 = 0.f, a1 = 0.f;
      const float* ez = A.enc_z + ((size_t)b*256)*512 + tid;
      #pragma unroll 16
      for (int q = 0; q < 256; ++q){
        float p = pL[q];
        a0 += p*ez[(size_t)q*512];
        a1 += p*ez[(size_t)q*512 + 256];
      }
      float* ac = A.att_c + par*16384 + b*512;
      stc(ac + tid, a0*inv);
      stc(ac + tid + 256, a1*inv);
    } else if (blk < 41 && t > 0){
      out_phase(A, A.z1 + (par^1)*16384, A.att_c + (par^1)*16384,
                t-1, blk, tid, Xl, Tg, L + O_EXT);
    }
    GBAR();

    // ========== P2: G0 + z0 finalize (L0) ; gpre1(t+1) (GP1) ==========
    if (isL0){
      const float* acb = A.att_c + par*16384;
      v4f q0,q1,q2,q3,q4,q5,q6,q7;
      v4f a0={0,0,0,0}, a1={0,0,0,0};
      PFI(acb, 0);
      PFW(Xl); PFI(acb, 256); gemmK256(W4, Xl, tid, a0, a1);
      PFW(Xl);                gemmK256(W4 + 4096, Xl, tid, a0, a1);
      int q = tid & 7, b = tid >> 3;
      __syncthreads();
      Tg[b*16 + q]     = hsum(a0);
      Tg[b*16 + q + 8] = hsum(a1);
      __syncthreads();
      if (tid < 128){
        int b2 = tid >> 2, ul = tid & 3;
        int u = blk*4 + ul;
        float gi = Tg[b2*16 + ul*4 + 0];
        float gf = Tg[b2*16 + ul*4 + 1];
        float gg = Tg[b2*16 + ul*4 + 2];
        float go = Tg[b2*16 + ul*4 + 3];
        v4f p0 = ldc4_nw(A.gpre0 + b2*2048 + u*4);
        v4f p1 = ldc4_nw(A.gpre1 + par*65536 + b2*2048 + u*4);
        waitvm2(p0, p1);
        v4f bs = *(const v4f*)&A.biasP0[u*4];
        gi += p0.x + p1.x + bs.x; gf += p0.y + p1.y + bs.y;
        gg += p0.z + p1.z + bs.z; go += p0.w + p1.w + bs.w;
        float co = SBc[tid], zo = SBz[tid];
        float c2 = sigf(gf)*co + sigf(gi)*tanhf(gg);
        float h  = sigf(go)*tanhf(c2);
        SBc[tid] = 0.1f*co + 0.9f*c2;
        float zn = 0.1f*zo + 0.9f*h;
        SBz[tid] = zn;
        stc(A.z0 + b2*512 + u, zn);
      }
    } else if (isGP1 && t < 255){
      gp1_phase(A, t+1, blk-128, tid, Xl, L + O_EXT);
    }
    GBAR();

    // ========== P3: LSTM1 + z1 finalize (L1) ; gpre0(+dec) prefetch (L0) ==========
    if (!isL0){
      const float* z1rd = A.z1 + (par^1)*16384;
      v4f q0,q1,q2,q3,q4,q5,q6,q7;
      v4f a0={0,0,0,0}, a1={0,0,0,0};
      PFI(A.z0, 0);
      PFW(Xl); PFI(A.z0, 256); gemmK256(W4,         Xl, tid, a0, a1);
      PFW(Xl); PFI(z1rd, 0);   gemmK256(W4 + 4096,  Xl, tid, a0, a1);
      PFW(Xl); PFI(z1rd, 256); gemmK256(W4 + 8192,  Xl, tid, a0, a1);
      PFW(Xl);                 gemmK256(W4 + 12288, Xl, tid, a0, a1);
      int q = tid & 7, b = tid >> 3;
      __syncthreads();
      Tg[b*16 + q]     = hsum(a0);
      Tg[b*16 + q + 8] = hsum(a1);
      __syncthreads();
      if (tid < 128){
        int b2 = tid >> 2, ul = tid & 3;
        int u = (blk-128)*4 + ul;
        float gi = Tg[b2*16 + ul*4 + 0];
        float gf = Tg[b2*16 + ul*4 + 1];
        float gg = Tg[b2*16 + ul*4 + 2];
        float go = Tg[b2*16 + ul*4 + 3];
        v4f bs = *(const v4f*)&A.biasP1[u*4];
        gi += bs.x; gf += bs.y; gg += bs.z; go += bs.w;
        float co = SBc[tid], zo = SBz[tid];
        float c2 = sigf(gf)*co + sigf(gi)*tanhf(gg);
        float h  = sigf(go)*tanhf(c2);
        SBc[tid] = 0.1f*co + 0.9f*c2;
        float zn = 0.1f*zo + 0.9f*h;
        SBz[tid] = zn;
        stc(A.z1 + par*16384 + b2*512 + u, zn);
      }
    } else if (t < 255){
      const float* Wd4 = L + O_EXT + 2048;
      v4f q0,q1,q2,q3,q4,q5,q6,q7;
      v4f a0={0,0,0,0}, a1={0,0,0,0};
      v4f dd4={0,0,0,0};
      int q = tid & 7, b = tid >> 3;
      PFI(A.z0, 0);
      PFW(Xl); PFI(A.z0, 256);
      gemmK256(W4 + 8192, Xl, tid, a0, a1);
      if (blk < 32){
        #pragma unroll 8
        for (int i = 0; i < 32; ++i){
          int kl = q*32 + i;
          dd4 += Xl[b*260 + kl] * (*(const v4f*)&Wd4[kl*4]);
        }
      }
      PFW(Xl);
      gemmK256(W4 + 12288, Xl, tid, a0, a1);
      if (blk < 32){
        #pragma unroll 8
        for (int i = 0; i < 32; ++i){
          int kl = q*32 + i;
          dd4 += Xl[b*260 + kl] * (*(const v4f*)&Wd4[(256+kl)*4]);
        }
        #pragma unroll
        for (int m = 1; m < 8; m <<= 1){
          dd4.x += __shfl_xor(dd4.x, m); dd4.y += __shfl_xor(dd4.y, m);
          dd4.z += __shfl_xor(dd4.z, m); dd4.w += __shfl_xor(dd4.w, m);
        }
        if (q == 0){
          float* dp = A.dec + b*128 + blk*4;
          stc(dp+0, dd4.x); stc(dp+1, dd4.y); stc(dp+2, dd4.z); stc(dp+3, dd4.w);
        }
      }
      float* dst = A.gpre0 + b*2048 + blk*16;
      stc(dst + q,     hsum(a0));
      stc(dst + q + 8, hsum(a1));
    }
    GBAR();
  }

  // ---- tail: out(255) ----
  if (blk < 41){
    out_phase(A, A.z1 + 16384, A.att_c + 16384, 255, blk, tid, Xl, Tg, L + O_EXT);
  }
  #undef GBAR
}

// ---------------- postnet conv (kernel=5, pad=2) as tiled GEMM ----------------
__global__ void __launch_bounds__(256) k_conv(const float* __restrict__ in,
                       const float* __restrict__ Wt,
                       const float* __restrict__ sc, const float* __restrict__ sh,
                       float* __restrict__ out0, const float* __restrict__ before,
                       float* __restrict__ after, int C, int N, int mode)
{
  __shared__ __align__(16) float As[16][64];
  __shared__ __align__(16) float Bs[16][64];
  int bx = blockIdx.x;
  int b = bx >> 2, l0 = (bx & 3)*64;
  int n0 = blockIdx.y*64;
  int tid = threadIdx.x, tx = tid & 15, ty = tid >> 4;
  float acc[4][4];
  #pragma unroll
  for (int i = 0; i < 4; ++i)
    #pragma unroll
    for (int j = 0; j < 4; ++j) acc[i][j] = 0.f;
  for (int k = 0; k < 5; ++k){
    int shift = k - 2;
    for (int c0 = 0; c0 < C; c0 += 16){
      #pragma unroll
      for (int i = 0; i < 4; ++i){
        int e = tid + i*256; int cc = e >> 6, ll = e & 63;
        int l = l0 + ll + shift;
        As[cc][ll] = ((unsigned)l < 256u) ? in[((size_t)(b*C + c0+cc))*256 + l] : 0.f;
        int n = n0 + ll;
        Bs[cc][ll] = (n < N) ? Wt[((size_t)k*C + c0+cc)*(size_t)N + n] : 0.f;
      }
      __syncthreads();
      #pragma unroll
      for (int cc = 0; cc < 16; ++cc){
        const float4 av = *reinterpret_cast<const float4*>(&As[cc][ty<<2]);
        const float4 bv = *reinterpret_cast<const float4*>(&Bs[cc][tx<<2]);
        acc[0][0]+=av.x*bv.x; acc[0][1]+=av.x*bv.y; acc[0][2]+=av.x*bv.z; acc[0][3]+=av.x*bv.w;
        acc[1][0]+=av.y*bv.x; acc[1][1]+=av.y*bv.y; acc[1][2]+=av.y*bv.z; acc[1][3]+=av.y*bv.w;
        acc[2][0]+=av.z*bv.x; acc[2][1]+=av.z*bv.y; acc[2][2]+=av.z*bv.z; acc[2][3]+=av.z*bv.w;
        acc[3][0]+=av.w*bv.x; acc[3][1]+=av.w*bv.y; acc[3][2]+=av.w*bv.z; acc[3][3]+=av.w*bv.w;
      }
      __syncthreads();
    }
  }
  #pragma unroll
  for (int i = 0; i < 4; ++i){
    int l = l0 + (ty<<2) + i;
    #pragma unroll
    for (int j = 0; j < 4; ++j){
      int n = n0 + (tx<<2) + j;
      if (n < N){
        float v = sc[n]*acc[i][j] + sh[n];
        if (mode == 0){
          out0[((size_t)(b*N + n))*256 + l] = tanhf(v);
        } else {
          size_t ob = ((size_t)b*256 + l)*80 + n;
          after[ob] = before[ob] + v;
        }
      }
    }
  }
}

extern "C" void kernel_launch(void* const* d_in, const int* in_sizes, int n_in,
                              void* d_out, int out_size, void* d_ws, size_t ws_size,
                              hipStream_t stream) {
  Args A;
  A.enc_z = (const float*)d_in[0];  A.ys = (const float*)d_in[1];
  A.ilens = (const int*)d_in[3];
  A.W_enc = (const float*)d_in[4];  A.b_enc = (const float*)d_in[5];
  A.W_dec = (const float*)d_in[6];  A.loc_kernel = (const float*)d_in[7];
  A.W_att = (const float*)d_in[8];  A.g_w = (const float*)d_in[9];  A.g_b = (const float*)d_in[10];
  A.Wp0 = (const float*)d_in[11];   A.bp0 = (const float*)d_in[12];
  A.Wp1 = (const float*)d_in[13];   A.bp1 = (const float*)d_in[14];
  A.Wih0 = (const float*)d_in[15];  A.Whh0 = (const float*)d_in[16];
  A.bih0 = (const float*)d_in[17];  A.bhh0 = (const float*)d_in[18];
  A.Wih1 = (const float*)d_in[19];  A.Whh1 = (const float*)d_in[20];
  A.bih1 = (const float*)d_in[21];  A.bhh1 = (const float*)d_in[22];
  A.Wf = (const float*)d_in[23];    A.bf = (const float*)d_in[24];
  A.Wq = (const float*)d_in[25];    A.bq = (const float*)d_in[26];
  A.pk0 = (const float*)d_in[27];   A.pb0 = (const float*)d_in[28];
  A.bg0 = (const float*)d_in[29];   A.bb0 = (const float*)d_in[30];
  A.pk1 = (const float*)d_in[31];   A.pb1 = (const float*)d_in[32];
  A.bg1 = (const float*)d_in[33];   A.bb1 = (const float*)d_in[34];
  A.pk2 = (const float*)d_in[35];   A.pb2 = (const float*)d_in[36];
  A.bg2 = (const float*)d_in[37];   A.bb2 = (const float*)d_in[38];

  float* ws = (float*)d_ws;
  size_t off = 0;
  auto alloc = [&](size_t n){ float* p = ws + off; off += n; return p; };
  A.enc_proj   = alloc(1048576);
  A.pre_tmp    = alloc(2097152);
  A.pre_all    = alloc(2097152);
  A.G          = alloc(3968);
  A.dec        = alloc(4096);
  A.att_c      = alloc(32768);
  A.z0         = alloc(16384);
  A.z1         = alloc(32768);
  A.gpre0      = alloc(65536);
  A.gpre1      = alloc(131072);
  A.biasP0     = alloc(2048);
  A.biasP1     = alloc(2048);
  A.before_t   = alloc(655360);
  A.h0         = alloc(4194304);
  A.h1         = alloc(4194304);
  A.Wt0        = alloc(204800);
  A.Wt1        = alloc(1310720);
  A.Wt2        = alloc(204800);
  A.s0 = alloc(512); A.t0s = alloc(512);
  A.s1 = alloc(512); A.t1s = alloc(512);
  A.s2 = alloc(128); A.t2s = alloc(128);
  A.bar = (int*)(ws + off); off += 4608;

  float* out = (float*)d_out;
  A.out_after  = out;
  A.out_before = out + 655360;
  A.out_logits = out + 1310720;
  A.out_aws    = out + 1318912;

  hipFuncSetAttribute((const void*)k_scan,
                      hipFuncAttributeMaxDynamicSharedMemorySize, DYN_LDS_BYTES);

  k_init<<<dim3(512), dim3(256), 0, stream>>>(A);
  k_encproj<<<dim3(256), dim3(256), 0, stream>>>(A);
  k_pre0<<<dim3(256), dim3(256), 0, stream>>>(A);
  k_pre1<<<dim3(256), dim3(256), 0, stream>>>(A);
  k_scan<<<dim3(NBLK), dim3(256), DYN_LDS_BYTES, stream>>>(A);
  k_conv<<<dim3(128,8), dim3(256), 0, stream>>>(A.before_t, A.Wt0, A.s0, A.t0s, A.h0, nullptr, nullptr, 80, 512, 0);
  k_conv<<<dim3(128,8), dim3(256), 0, stream>>>(A.h0, A.Wt1, A.s1, A.t1s, A.h1, nullptr, nullptr, 512, 512, 0);
  k_conv<<<dim3(128,2), dim3(256), 0, stream>>>(A.h1, A.Wt2, A.s2, A.t2s, nullptr, A.out_before, A.out_after, 512, 80, 1);
}

// Round 6
// 32773.529 us; speedup vs baseline: 1.9303x; 1.9303x over previous
//
#include <hip/hip_runtime.h>
#include <cstdint>

#define LSEQ 256
#define BN_INV 0.99999500003750f

typedef float v4f __attribute__((ext_vector_type(4)));

#define DYN_B 68224    // (8320 Xl + 544 Tg + 8192 W) *4
#define DYN_C 100992   // (8320 Xl + 544 Tg + 16384 W) *4

struct Args {
  const float *enc_z, *ys;
  const int* ilens;
  const float *W_enc, *b_enc, *W_dec, *loc_kernel, *W_att, *g_w, *g_b;
  const float *Wp0, *bp0, *Wp1, *bp1;
  const float *Wih0, *Whh0, *bih0, *bhh0, *Wih1, *Whh1, *bih1, *bhh1;
  const float *Wf, *bf, *Wq, *bq;
  const float *pk0,*pb0,*bg0,*bb0,*pk1,*pb1,*bg1,*bb1,*pk2,*pb2,*bg2,*bb2;
  float *enc_proj, *pre_tmp, *pre_all, *G, *dec, *att_c;
  float *z0, *z1, *c0g, *c1g, *gpre0, *gpre1, *biasP0, *biasP1;
  float *before_t, *h0, *h1, *Wt0, *Wt1, *Wt2, *s0, *t0s, *s1, *t1s, *s2, *t2s;
  float *W0pack, *W1pack, *Wp1pack, *WFpack, *Wdpack;
  float *out_after, *out_before, *out_logits, *out_aws;
};

__device__ __forceinline__ float sigf(float x){ return 1.0f/(1.0f+expf(-x)); }
__device__ __forceinline__ float hsum(const v4f& v){ return v.x+v.y+v.z+v.w; }

// ---------------- init: precomputes + per-block weight packs ----------------
__global__ void k_init(Args A){
  int tid0 = blockIdx.x*blockDim.x + threadIdx.x;
  int stride = gridDim.x*blockDim.x;
  for (int i = tid0; i < 31*128; i += stride){
    int k = i >> 7, d = i & 127;
    float s = 0.f;
    for (int c = 0; c < 32; ++c) s += A.W_att[c*128+d]*A.loc_kernel[c*31+k];
    A.G[i] = s;
  }
  for (int i = tid0; i < 2048; i += stride){
    int u = i & 511, g = i >> 9;
    A.biasP0[u*4+g] = A.bih0[i]+A.bhh0[i];
    A.biasP1[u*4+g] = A.bih1[i]+A.bhh1[i];
  }
  for (int i = tid0; i < 16384; i += stride){ A.z0[i]=0.f; A.c0g[i]=0.f; A.c1g[i]=0.f; }
  for (int i = tid0; i < 32768; i += stride) A.z1[i]=0.f;
  for (int i = tid0; i < 65536; i += stride) A.gpre0[i]=0.f;
  for (int i = tid0; i < 4096; i += stride) A.dec[i]=0.f;
  for (int i = tid0; i < 512; i += stride){
    float s = A.bg0[i]*BN_INV; A.s0[i]=s; A.t0s[i]=s*A.pb0[i]+A.bb0[i];
    float u = A.bg1[i]*BN_INV; A.s1[i]=u; A.t1s[i]=u*A.pb1[i]+A.bb1[i];
  }
  for (int i = tid0; i < 80; i += stride){
    float s = A.bg2[i]*BN_INV; A.s2[i]=s; A.t2s[i]=s*A.pb2[i]+A.bb2[i];
  }
  for (int i = tid0; i < 5*80*512; i += stride){
    int k = i/(80*512); int r = i - k*(80*512); int c = r>>9, n = r&511;
    A.Wt0[i] = A.pk0[(n*80+c)*5+k];
  }
  for (int i = tid0; i < 5*512*512; i += stride){
    int k = i/(512*512); int r = i - k*(512*512); int c = r>>9, n = r&511;
    A.Wt1[i] = A.pk1[(n*512+c)*5+k];
  }
  for (int i = tid0; i < 5*512*80; i += stride){
    int k = i/(512*80); int r = i - k*(512*80); int c = r/80, n = r - c*80;
    A.Wt2[i] = A.pk2[(n*512+c)*5+k];
  }
  // ---- per-block weight packs (LDS image order => coalesced reload each launch) ----
  for (int i = tid0; i < 128*16384; i += stride){
    int blk = i >> 14, idx = i & 16383;
    int kq = idx >> 6, rem = idx & 63, p = rem >> 2, kl = rem & 3;
    int k = kq*4 + kl;
    int gcol = (p & 3)*512 + blk*4 + (p >> 2);
    A.W0pack[i] = (k < 512) ? A.Wih0[(size_t)k*2048 + gcol]
                            : A.Whh0[(size_t)(k-512)*2048 + gcol];
  }
  for (int i = tid0; i < 128*16384; i += stride){
    int blk = i >> 14, idx = i & 16383;
    int kq = idx >> 6, rem = idx & 63, p = rem >> 2, kl = rem & 3;
    int k = kq*4 + kl;
    int gcol = (p & 3)*512 + blk*4 + (p >> 2);
    A.W1pack[i] = (k < 512) ? A.Wih1[(size_t)k*2048 + gcol]
                            : A.Whh1[(size_t)(k-512)*2048 + gcol];
  }
  for (int i = tid0; i < 64*8192; i += stride){
    int m = i >> 13, idx = i & 8191;
    int kq = idx >> 7, rem = idx & 127, p = rem >> 2, kl = rem & 3;
    int k = kq*4 + kl;
    int gcol = (p & 3)*512 + m*8 + (p >> 2);
    A.Wp1pack[i] = A.Wih0[(size_t)(512+k)*2048 + gcol];
  }
  for (int i = tid0; i < 41*2048; i += stride){
    int blk = i >> 11, k2 = i & 2047;
    int k = k2 >> 1, e = k2 & 1, c = blk*2 + e;
    A.WFpack[i] = (c < 80) ? A.Wf[(size_t)k*80 + c] : A.Wq[k];
  }
  for (int i = tid0; i < 32*2048; i += stride){
    int blk = i >> 11, j = i & 2047;
    int k = j >> 2, c = j & 3;
    A.Wdpack[i] = A.W_dec[(size_t)k*128 + blk*4 + c];
  }
}

// ---------------- enc_proj ----------------
__global__ void __launch_bounds__(256) k_encproj(Args A){
  __shared__ __align__(16) float As[32][128];
  int m0 = blockIdx.x*32;
  int tid = threadIdx.x;
  int d = tid & 127, half = tid >> 7;
  float acc[16];
  #pragma unroll
  for (int r = 0; r < 16; ++r) acc[r] = 0.f;
  for (int j0 = 0; j0 < 512; j0 += 128){
    for (int i = 0; i < 16; ++i){
      int e = tid + i*256; int r = e >> 7, j = e & 127;
      As[r][j] = A.enc_z[(size_t)(m0+r)*512 + j0 + j];
    }
    __syncthreads();
    for (int j = 0; j < 128; ++j){
      float w = A.W_enc[(size_t)(j0+j)*128 + d];
      #pragma unroll
      for (int r = 0; r < 16; ++r) acc[r] += As[half*16+r][j]*w;
    }
    __syncthreads();
  }
  float be = A.b_enc[d];
  for (int r = 0; r < 16; ++r)
    A.enc_proj[(size_t)(m0+half*16+r)*128 + d] = acc[r] + be;
}

// ---------------- prenet ----------------
__global__ void __launch_bounds__(256) k_pre0(Args A){
  __shared__ float As[32][80];
  int m0 = blockIdx.x*32, tid = threadIdx.x;
  for (int e = tid; e < 2560; e += 256){
    int r = e/80, o = e - r*80;
    int row = m0+r; int l = row & 255, b = row >> 8;
    As[r][o] = (l==0) ? 0.f : A.ys[((size_t)b*256 + (l-1))*80 + o];
  }
  __syncthreads();
  float acc[32];
  #pragma unroll
  for (int r = 0; r < 32; ++r) acc[r] = 0.f;
  for (int o = 0; o < 80; ++o){
    float w = A.Wp0[o*256 + tid];
    #pragma unroll
    for (int r = 0; r < 32; ++r) acc[r] += As[r][o]*w;
  }
  float bb = A.bp0[tid];
  for (int r = 0; r < 32; ++r){
    float v = acc[r]+bb;
    A.pre_tmp[(size_t)(m0+r)*256 + tid] = v>0.f?v:0.f;
  }
}

__global__ void __launch_bounds__(256) k_pre1(Args A){
  __shared__ float As[32][256];
  int m0 = blockIdx.x*32, tid = threadIdx.x;
  for (int e = tid; e < 8192; e += 256){
    int r = e >> 8, j = e & 255;
    As[r][j] = A.pre_tmp[(size_t)(m0+r)*256 + j];
  }
  __syncthreads();
  float acc[32];
  #pragma unroll
  for (int r = 0; r < 32; ++r) acc[r] = 0.f;
  for (int j = 0; j < 256; ++j){
    float w = A.Wp1[j*256 + tid];
    #pragma unroll
    for (int r = 0; r < 32; ++r) acc[r] += As[r][j]*w;
  }
  float bb = A.bp1[tid];
  for (int r = 0; r < 32; ++r){
    float v = acc[r]+bb;
    A.pre_all[(size_t)(m0+r)*256 + tid] = v>0.f?v:0.f;
  }
}

// ---- stage 32 rows x 256 floats into LDS (pitch 260), plain cached loads ----
__device__ __forceinline__ void stage256(const float* base, int rowstride, int koff,
                                         float* Xl, int tid){
  v4f r0,r1,r2,r3,r4,r5,r6,r7;
  #define LDX(i,dst) { int f=tid+((i)<<8); int b=f>>6; int jq=f&63; \
      dst = *(const v4f*)(base + (size_t)b*rowstride + koff + jq*4); }
  LDX(0,r0) LDX(1,r1) LDX(2,r2) LDX(3,r3) LDX(4,r4) LDX(5,r5) LDX(6,r6) LDX(7,r7)
  #undef LDX
  __syncthreads();
  #define STX(i,src) { int f=tid+((i)<<8); int b=f>>6; int jq=f&63; \
      *(v4f*)&Xl[b*260 + jq*4] = src; }
  STX(0,r0) STX(1,r1) STX(2,r2) STX(3,r3) STX(4,r4) STX(5,r5) STX(6,r6) STX(7,r7)
  #undef STX
  __syncthreads();
}

// ---- K=256 chunk gemm: W4 image [kq][16 cols][4]; thread -> cols (tid&7),(tid&7)+8 ----
__device__ __forceinline__ void gemmK256(const float* __restrict__ W4,
                                         const float* __restrict__ Xl,
                                         int tid, v4f& a0, v4f& a1){
  const int q = tid & 7, b = tid >> 3;
  const float* xr = Xl + b*260;
  #pragma unroll 8
  for (int jq = 0; jq < 64; ++jq){
    v4f xv = *(const v4f*)&xr[jq*4];
    v4f w0 = *(const v4f*)&W4[jq*64 + q*4];
    v4f w1 = *(const v4f*)&W4[jq*64 + (q+8)*4];
    a0 += xv*w0; a1 += xv*w1;
  }
}

// ---- out(tt): 2 cols of [Wf|Wq], K=1024 over [z1; att_c] ----
__device__ __forceinline__ void out_phase(const Args& A, const float* z1b, const float* acb,
                                          int tt, int ob, int tid, float* Xl, float* Tg,
                                          const float* WF){
  int b = tid >> 3, sub = tid & 7;
  float acc0 = 0.f, acc1 = 0.f;
  for (int pass = 0; pass < 4; ++pass){
    const float* src = (pass < 2) ? z1b : acb;
    stage256(src, 512, (pass & 1)*256, Xl, tid);
    int kbase = pass*256;
    #pragma unroll 4
    for (int i = 0; i < 32; ++i){
      int k = sub + 8*i;
      float x = Xl[b*260 + k];
      acc0 += x*WF[(kbase+k)*2 + 0];
      acc1 += x*WF[(kbase+k)*2 + 1];
    }
    __syncthreads();
  }
  Tg[(b*8+sub)*2+0] = acc0; Tg[(b*8+sub)*2+1] = acc1;
  __syncthreads();
  if (tid < 64){
    int b2 = tid >> 1, e = tid & 1, cg = ob*2 + e;
    float v = (cg < 80) ? A.bf[cg] : A.bq[0];
    for (int s = 0; s < 8; ++s) v += Tg[(b2*8+s)*2 + e];
    if (cg < 80){
      A.out_before[((size_t)b2*256 + tt)*80 + cg] = v;
      A.before_t[((size_t)b2*80 + cg)*256 + tt] = v;
    } else if (cg == 80){
      A.out_logits[(size_t)b2*256 + tt] = v;
    }
  }
}

// ---- gpre1(tp): one block = 8 units (32 gate-cols), K=256 over pre(tp) ----
__device__ __forceinline__ void gp1_body(const Args& A, int tp, int m2, int tid,
                                         float* Xl, const float* Wp4){
  stage256(A.pre_all + (size_t)tp*256, 65536, 0, Xl, tid);
  int q = tid & 7, b = tid >> 3;
  v4f a0={0,0,0,0}, a1={0,0,0,0}, a2={0,0,0,0}, a3={0,0,0,0};
  const float* xr = Xl + b*260;
  #pragma unroll 8
  for (int jq = 0; jq < 64; ++jq){
    v4f xv = *(const v4f*)&xr[jq*4];
    a0 += xv * (*(const v4f*)&Wp4[jq*128 + q*4]);
    a1 += xv * (*(const v4f*)&Wp4[jq*128 + (q+8)*4]);
    a2 += xv * (*(const v4f*)&Wp4[jq*128 + (q+16)*4]);
    a3 += xv * (*(const v4f*)&Wp4[jq*128 + (q+24)*4]);
  }
  float* dst = A.gpre1 + (tp&1)*65536 + b*2048 + m2*32;
  dst[q]      = hsum(a0);
  dst[q + 8]  = hsum(a1);
  dst[q + 16] = hsum(a2);
  dst[q + 24] = hsum(a3);
}

// ---------------- per-step kernel A: attention for b = blockIdx.x ----------------
__global__ void __launch_bounds__(256) k_att(Args A, int t){
  __shared__ __align__(16) float Gs[3968];
  __shared__ float awin[288];
  __shared__ float pL[256];
  __shared__ __align__(16) float decs[128];
  __shared__ float red[4];
  int b = blockIdx.x, tid = threadIdx.x;
  int par = t & 1;
  int il = A.ilens[b];
  for (int e = tid; e < 3968; e += 256) Gs[e] = A.G[e];
  for (int i = tid; i < 288; i += 256){
    int tt = i - 15;
    float v = 0.f;
    if ((unsigned)tt < 256u)
      v = t ? A.out_aws[((size_t)b*256 + (t-1))*256 + tt]
            : ((tt < il) ? 1.0f/(float)il : 0.f);
    awin[i] = v;
  }
  if (tid < 128) decs[tid] = A.dec[b*128 + tid];
  __syncthreads();
  float gb = A.g_b[0];
  int dg = tid & 7, ttg = tid >> 3;
  int d0 = dg*16, tt0 = ttg*8;
  float ebuf[8];
  #pragma unroll
  for (int h = 0; h < 2; ++h){
    int ttb = tt0 + h*4;
    float aw[34];
    #pragma unroll
    for (int i = 0; i < 34; ++i) aw[i] = awin[ttb + i];
    v4f acc[4][4];
    #pragma unroll
    for (int i = 0; i < 4; ++i)
      #pragma unroll
      for (int r = 0; r < 4; ++r) acc[i][r] = (v4f){0.f,0.f,0.f,0.f};
    #pragma unroll
    for (int k = 0; k < 31; ++k){
      const float* gp = &Gs[k*128 + d0];
      v4f g0 = *(const v4f*)&gp[0],  g1 = *(const v4f*)&gp[4];
      v4f g2 = *(const v4f*)&gp[8],  g3 = *(const v4f*)&gp[12];
      #pragma unroll
      for (int i = 0; i < 4; ++i){
        float a = aw[i + k];
        acc[i][0] += g0*a; acc[i][1] += g1*a; acc[i][2] += g2*a; acc[i][3] += g3*a;
      }
    }
    #pragma unroll
    for (int i = 0; i < 4; ++i){
      int tt = ttb + i;
      const float* ep = A.enc_proj + ((size_t)b*256 + tt)*128 + d0;
      float s = 0.f;
      #pragma unroll
      for (int r = 0; r < 4; ++r){
        v4f v = acc[i][r] + *(const v4f*)&ep[r*4] + *(const v4f*)&decs[d0 + r*4];
        v4f gv = *(const v4f*)&A.g_w[d0 + r*4];
        s += tanhf(v.x)*gv.x + tanhf(v.y)*gv.y + tanhf(v.z)*gv.z + tanhf(v.w)*gv.w;
      }
      s += __shfl_xor(s,1); s += __shfl_xor(s,2); s += __shfl_xor(s,4);
      ebuf[h*4+i] = s;
    }
  }
  if (dg == 0){
    #pragma unroll
    for (int i = 0; i < 8; ++i){
      int tt = tt0 + i;
      float e = ebuf[i] + gb;
      pL[tt] = (tt < il) ? expf(2.0f*e) : 0.0f;
    }
  }
  __syncthreads();
  float pv = pL[tid];
  {
    float v = pv;
    v += __shfl_xor(v,1); v += __shfl_xor(v,2); v += __shfl_xor(v,4);
    v += __shfl_xor(v,8); v += __shfl_xor(v,16); v += __shfl_xor(v,32);
    if ((tid & 63) == 0) red[tid>>6] = v;
  }
  __syncthreads();
  float inv = 1.0f/(red[0]+red[1]+red[2]+red[3]);
  A.out_aws[((size_t)b*256 + t)*256 + tid] = pv*inv;
  float a0 = 0.f, a1 = 0.f;
  const float* ez = A.enc_z + ((size_t)b*256)*512 + tid;
  #pragma unroll 16
  for (int q = 0; q < 256; ++q){
    float p = pL[q];
    a0 += p*ez[(size_t)q*512];
    a1 += p*ez[(size_t)q*512 + 256];
  }
  float* ac = A.att_c + par*16384 + b*512;
  ac[tid] = a0*inv;
  ac[tid + 256] = a1*inv;
}

// ---------------- per-step kernel B: L0 gates+z0 | gpre1(t+1) | out(t-1) ----------------
__global__ void __launch_bounds__(256, 1) k_phaseB(Args A, int t){
  extern __shared__ float L[];
  float* Xl = L;            // 8320
  float* Tg = L + 8320;     // 544
  float* W4 = L + 8864;     // up to 8192 here
  int blk = blockIdx.x, tid = threadIdx.x;
  int par = t & 1;
  if (blk < 128){
    const float* src = A.W0pack + (size_t)blk*16384;   // first 8192 = Wih0 (K=512)
    for (int i = tid*4; i < 8192; i += 1024) *(v4f*)&W4[i] = *(const v4f*)&src[i];
    __syncthreads();
    const float* acb = A.att_c + par*16384;
    v4f a0={0,0,0,0}, a1={0,0,0,0};
    stage256(acb, 512, 0, Xl, tid);   gemmK256(W4,        Xl, tid, a0, a1);
    stage256(acb, 512, 256, Xl, tid); gemmK256(W4 + 4096, Xl, tid, a0, a1);
    int q = tid & 7, b = tid >> 3;
    __syncthreads();
    Tg[b*16 + q]     = hsum(a0);
    Tg[b*16 + q + 8] = hsum(a1);
    __syncthreads();
    if (tid < 128){
      int b2 = tid >> 2, ul = tid & 3;
      int u = blk*4 + ul;
      float gi = Tg[b2*16 + ul*4 + 0];
      float gf = Tg[b2*16 + ul*4 + 1];
      float gg = Tg[b2*16 + ul*4 + 2];
      float go = Tg[b2*16 + ul*4 + 3];
      v4f p0 = *(const v4f*)&A.gpre0[b2*2048 + u*4];
      v4f p1 = *(const v4f*)&A.gpre1[par*65536 + b2*2048 + u*4];
      v4f bs = *(const v4f*)&A.biasP0[u*4];
      gi += p0.x + p1.x + bs.x; gf += p0.y + p1.y + bs.y;
      gg += p0.z + p1.z + bs.z; go += p0.w + p1.w + bs.w;
      float co = A.c0g[b2*512 + u], zo = A.z0[b2*512 + u];
      float c2 = sigf(gf)*co + sigf(gi)*tanhf(gg);
      float h  = sigf(go)*tanhf(c2);
      A.c0g[b2*512 + u] = 0.1f*co + 0.9f*c2;
      A.z0[b2*512 + u]  = 0.1f*zo + 0.9f*h;
    }
  } else if (blk < 192){
    if (t < 255){
      int m2 = blk - 128;
      const float* src = A.Wp1pack + (size_t)m2*8192;
      for (int i = tid*4; i < 8192; i += 1024) *(v4f*)&W4[i] = *(const v4f*)&src[i];
      __syncthreads();
      gp1_body(A, t+1, m2, tid, Xl, W4);
    }
  } else {
    if (t > 0){
      int ob = blk - 192;
      const float* src = A.WFpack + (size_t)ob*2048;
      for (int i = tid; i < 2048; i += 256) W4[i] = src[i];
      __syncthreads();
      out_phase(A, A.z1 + (par^1)*16384, A.att_c + (par^1)*16384,
                t-1, ob, tid, Xl, Tg, W4);
    }
  }
}

// ---------------- per-step kernel C: gpre0/dec prefetch (blk<128) | LSTM1 (blk>=128) ----
__global__ void __launch_bounds__(256, 1) k_phaseC(Args A, int t){
  extern __shared__ float L[];
  float* Xl = L;            // 8320
  float* Tg = L + 8320;     // 544
  float* W4 = L + 8864;     // 8192 (gpre0) or 16384 (LSTM1)
  float* Wd = L + 17056;    // 2048 (dec blocks)
  int blk = blockIdx.x, tid = threadIdx.x;
  int par = t & 1;
  if (blk >= 128){
    int m = blk - 128;
    const float* src = A.W1pack + (size_t)m*16384;
    for (int i = tid*4; i < 16384; i += 1024) *(v4f*)&W4[i] = *(const v4f*)&src[i];
    __syncthreads();
    const float* z1rd = A.z1 + (par^1)*16384;
    v4f a0={0,0,0,0}, a1={0,0,0,0};
    stage256(A.z0, 512, 0,   Xl, tid); gemmK256(W4,         Xl, tid, a0, a1);
    stage256(A.z0, 512, 256, Xl, tid); gemmK256(W4 + 4096,  Xl, tid, a0, a1);
    stage256(z1rd, 512, 0,   Xl, tid); gemmK256(W4 + 8192,  Xl, tid, a0, a1);
    stage256(z1rd, 512, 256, Xl, tid); gemmK256(W4 + 12288, Xl, tid, a0, a1);
    int q = tid & 7, b = tid >> 3;
    __syncthreads();
    Tg[b*16 + q]     = hsum(a0);
    Tg[b*16 + q + 8] = hsum(a1);
    __syncthreads();
    if (tid < 128){
      int b2 = tid >> 2, ul = tid & 3;
      int u = m*4 + ul;
      float gi = Tg[b2*16 + ul*4 + 0];
      float gf = Tg[b2*16 + ul*4 + 1];
      float gg = Tg[b2*16 + ul*4 + 2];
      float go = Tg[b2*16 + ul*4 + 3];
      v4f bs = *(const v4f*)&A.biasP1[u*4];
      gi += bs.x; gf += bs.y; gg += bs.z; go += bs.w;
      float co = A.c1g[b2*512 + u];
      float zo = A.z1[(par^1)*16384 + b2*512 + u];
      float c2 = sigf(gf)*co + sigf(gi)*tanhf(gg);
      float h  = sigf(go)*tanhf(c2);
      A.c1g[b2*512 + u] = 0.1f*co + 0.9f*c2;
      A.z1[par*16384 + b2*512 + u] = 0.1f*zo + 0.9f*h;
    }
  } else if (t < 255){
    const float* src = A.W0pack + (size_t)blk*16384 + 8192;   // Whh0 half
    for (int i = tid*4; i < 8192; i += 1024) *(v4f*)&W4[i] = *(const v4f*)&src[i];
    if (blk < 32){
      const float* sd = A.Wdpack + (size_t)blk*2048;
      for (int i = tid; i < 2048; i += 256) Wd[i] = sd[i];
    }
    __syncthreads();
    v4f a0={0,0,0,0}, a1={0,0,0,0};
    v4f dd4={0,0,0,0};
    int q = tid & 7, b = tid >> 3;
    stage256(A.z0, 512, 0, Xl, tid);
    gemmK256(W4, Xl, tid, a0, a1);
    if (blk < 32){
      #pragma unroll 8
      for (int i = 0; i < 32; ++i){
        int kl = q*32 + i;
        dd4 += Xl[b*260 + kl] * (*(const v4f*)&Wd[kl*4]);
      }
    }
    stage256(A.z0, 512, 256, Xl, tid);
    gemmK256(W4 + 4096, Xl, tid, a0, a1);
    if (blk < 32){
      #pragma unroll 8
      for (int i = 0; i < 32; ++i){
        int kl = q*32 + i;
        dd4 += Xl[b*260 + kl] * (*(const v4f*)&Wd[(256+kl)*4]);
      }
      #pragma unroll
      for (int m = 1; m < 8; m <<= 1){
        dd4.x += __shfl_xor(dd4.x, m); dd4.y += __shfl_xor(dd4.y, m);
        dd4.z += __shfl_xor(dd4.z, m); dd4.w += __shfl_xor(dd4.w, m);
      }
      if (q == 0) *(v4f*)&A.dec[b*128 + blk*4] = dd4;
    }
    float* dst = A.gpre0 + b*2048 + blk*16;
    dst[q]     = hsum(a0);
    dst[q + 8] = hsum(a1);
  }
}

// ---------------- gpre1 bootstrap (t=0) ----------------
__global__ void __launch_bounds__(256, 1) k_gp1init(Args A){
  extern __shared__ float L[];
  float* Xl = L;
  float* W4 = L + 8864;
  int m2 = blockIdx.x, tid = threadIdx.x;
  const float* src = A.Wp1pack + (size_t)m2*8192;
  for (int i = tid*4; i < 8192; i += 1024) *(v4f*)&W4[i] = *(const v4f*)&src[i];
  __syncthreads();
  gp1_body(A, 0, m2, tid, Xl, W4);
}

// ---------------- out(255) tail ----------------
__global__ void __launch_bounds__(256, 1) k_outlast(Args A){
  extern __shared__ float L[];
  float* Xl = L;
  float* Tg = L + 8320;
  float* WF = L + 8864;
  int ob = blockIdx.x, tid = threadIdx.x;
  const float* src = A.WFpack + (size_t)ob*2048;
  for (int i = tid; i < 2048; i += 256) WF[i] = src[i];
  __syncthreads();
  out_phase(A, A.z1 + 16384, A.att_c + 16384, 255, ob, tid, Xl, Tg, WF);
}

// ---------------- postnet conv (kernel=5, pad=2) as tiled GEMM ----------------
__global__ void __launch_bounds__(256) k_conv(const float* __restrict__ in,
                       const float* __restrict__ Wt,
                       const float* __restrict__ sc, const float* __restrict__ sh,
                       float* __restrict__ out0, const float* __restrict__ before,
                       float* __restrict__ after, int C, int N, int mode)
{
  __shared__ __align__(16) float As[16][64];
  __shared__ __align__(16) float Bs[16][64];
  int bx = blockIdx.x;
  int b = bx >> 2, l0 = (bx & 3)*64;
  int n0 = blockIdx.y*64;
  int tid = threadIdx.x, tx = tid & 15, ty = tid >> 4;
  float acc[4][4];
  #pragma unroll
  for (int i = 0; i < 4; ++i)
    #pragma unroll
    for (int j = 0; j < 4; ++j) acc[i][j] = 0.f;
  for (int k = 0; k < 5; ++k){
    int shift = k - 2;
    for (int c0 = 0; c0 < C; c0 += 16){
      #pragma unroll
      for (int i = 0; i < 4; ++i){
        int e = tid + i*256; int cc = e >> 6, ll = e & 63;
        int l = l0 + ll + shift;
        As[cc][ll] = ((unsigned)l < 256u) ? in[((size_t)(b*C + c0+cc))*256 + l] : 0.f;
        int n = n0 + ll;
        Bs[cc][ll] = (n < N) ? Wt[((size_t)k*C + c0+cc)*(size_t)N + n] : 0.f;
      }
      __syncthreads();
      #pragma unroll
      for (int cc = 0; cc < 16; ++cc){
        const float4 av = *reinterpret_cast<const float4*>(&As[cc][ty<<2]);
        const float4 bv = *reinterpret_cast<const float4*>(&Bs[cc][tx<<2]);
        acc[0][0]+=av.x*bv.x; acc[0][1]+=av.x*bv.y; acc[0][2]+=av.x*bv.z; acc[0][3]+=av.x*bv.w;
        acc[1][0]+=av.y*bv.x; acc[1][1]+=av.y*bv.y; acc[1][2]+=av.y*bv.z; acc[1][3]+=av.y*bv.w;
        acc[2][0]+=av.z*bv.x; acc[2][1]+=av.z*bv.y; acc[2][2]+=av.z*bv.z; acc[2][3]+=av.z*bv.w;
        acc[3][0]+=av.w*bv.x; acc[3][1]+=av.w*bv.y; acc[3][2]+=av.w*bv.z; acc[3][3]+=av.w*bv.w;
      }
      __syncthreads();
    }
  }
  #pragma unroll
  for (int i = 0; i < 4; ++i){
    int l = l0 + (ty<<2) + i;
    #pragma unroll
    for (int j = 0; j < 4; ++j){
      int n = n0 + (tx<<2) + j;
      if (n < N){
        float v = sc[n]*acc[i][j] + sh[n];
        if (mode == 0){
          out0[((size_t)(b*N + n))*256 + l] = tanhf(v);
        } else {
          size_t ob2 = ((size_t)b*256 + l)*80 + n;
          after[ob2] = before[ob2] + v;
        }
      }
    }
  }
}

extern "C" void kernel_launch(void* const* d_in, const int* in_sizes, int n_in,
                              void* d_out, int out_size, void* d_ws, size_t ws_size,
                              hipStream_t stream) {
  Args A;
  A.enc_z = (const float*)d_in[0];  A.ys = (const float*)d_in[1];
  A.ilens = (const int*)d_in[3];
  A.W_enc = (const float*)d_in[4];  A.b_enc = (const float*)d_in[5];
  A.W_dec = (const float*)d_in[6];  A.loc_kernel = (const float*)d_in[7];
  A.W_att = (const float*)d_in[8];  A.g_w = (const float*)d_in[9];  A.g_b = (const float*)d_in[10];
  A.Wp0 = (const float*)d_in[11];   A.bp0 = (const float*)d_in[12];
  A.Wp1 = (const float*)d_in[13];   A.bp1 = (const float*)d_in[14];
  A.Wih0 = (const float*)d_in[15];  A.Whh0 = (const float*)d_in[16];
  A.bih0 = (const float*)d_in[17];  A.bhh0 = (const float*)d_in[18];
  A.Wih1 = (const float*)d_in[19];  A.Whh1 = (const float*)d_in[20];
  A.bih1 = (const float*)d_in[21];  A.bhh1 = (const float*)d_in[22];
  A.Wf = (const float*)d_in[23];    A.bf = (const float*)d_in[24];
  A.Wq = (const float*)d_in[25];    A.bq = (const float*)d_in[26];
  A.pk0 = (const float*)d_in[27];   A.pb0 = (const float*)d_in[28];
  A.bg0 = (const float*)d_in[29];   A.bb0 = (const float*)d_in[30];
  A.pk1 = (const float*)d_in[31];   A.pb1 = (const float*)d_in[32];
  A.bg1 = (const float*)d_in[33];   A.bb1 = (const float*)d_in[34];
  A.pk2 = (const float*)d_in[35];   A.pb2 = (const float*)d_in[36];
  A.bg2 = (const float*)d_in[37];   A.bb2 = (const float*)d_in[38];

  float* ws = (float*)d_ws;
  size_t off = 0;
  auto alloc = [&](size_t n){ float* p = ws + off; off += n; return p; };
  A.enc_proj   = alloc(1048576);
  A.pre_tmp    = alloc(2097152);
  A.pre_all    = alloc(2097152);
  A.G          = alloc(3968);
  A.dec        = alloc(4096);
  A.att_c      = alloc(32768);
  A.z0         = alloc(16384);
  A.z1         = alloc(32768);
  A.c0g        = alloc(16384);
  A.c1g        = alloc(16384);
  A.gpre0      = alloc(65536);
  A.gpre1      = alloc(131072);
  A.biasP0     = alloc(2048);
  A.biasP1     = alloc(2048);
  A.before_t   = alloc(655360);
  A.h0         = alloc(4194304);
  A.h1         = alloc(4194304);
  A.Wt0        = alloc(204800);
  A.Wt1        = alloc(1310720);
  A.Wt2        = alloc(204800);
  A.s0 = alloc(512); A.t0s = alloc(512);
  A.s1 = alloc(512); A.t1s = alloc(512);
  A.s2 = alloc(128); A.t2s = alloc(128);
  // weight packs alias the postnet activation buffers (used before postnet runs;
  // k_init refills them at the start of every replay)
  A.W0pack  = A.h0;                       // 128*16384 = 2097152
  A.W1pack  = A.h0 + 2097152;             // 2097152 (h0 is 4194304 total)
  A.Wp1pack = A.h1;                       // 64*8192 = 524288
  A.WFpack  = A.h1 + 524288;              // 41*2048 = 83968
  A.Wdpack  = A.h1 + 524288 + 83968;      // 32*2048 = 65536

  float* out = (float*)d_out;
  A.out_after  = out;
  A.out_before = out + 655360;
  A.out_logits = out + 1310720;
  A.out_aws    = out + 1318912;

  hipFuncSetAttribute((const void*)k_phaseB,
                      hipFuncAttributeMaxDynamicSharedMemorySize, DYN_B);
  hipFuncSetAttribute((const void*)k_phaseC,
                      hipFuncAttributeMaxDynamicSharedMemorySize, DYN_C);
  hipFuncSetAttribute((const void*)k_gp1init,
                      hipFuncAttributeMaxDynamicSharedMemorySize, DYN_B);
  hipFuncSetAttribute((const void*)k_outlast,
                      hipFuncAttributeMaxDynamicSharedMemorySize, DYN_B);

  k_init<<<dim3(1024), dim3(256), 0, stream>>>(A);
  k_encproj<<<dim3(256), dim3(256), 0, stream>>>(A);
  k_pre0<<<dim3(256), dim3(256), 0, stream>>>(A);
  k_pre1<<<dim3(256), dim3(256), 0, stream>>>(A);
  k_gp1init<<<dim3(64), dim3(256), DYN_B, stream>>>(A);
  for (int t = 0; t < LSEQ; ++t){
    k_att<<<dim3(32), dim3(256), 0, stream>>>(A, t);
    k_phaseB<<<dim3(233), dim3(256), DYN_B, stream>>>(A, t);
    k_phaseC<<<dim3(256), dim3(256), DYN_C, stream>>>(A, t);
  }
  k_outlast<<<dim3(41), dim3(256), DYN_B, stream>>>(A);
  k_conv<<<dim3(128,8), dim3(256), 0, stream>>>(A.before_t, A.Wt0, A.s0, A.t0s, A.h0, nullptr, nullptr, 80, 512, 0);
  k_conv<<<dim3(128,8), dim3(256), 0, stream>>>(A.h0, A.Wt1, A.s1, A.t1s, A.h1, nullptr, nullptr, 512, 512, 0);
  k_conv<<<dim3(128,2), dim3(256), 0, stream>>>(A.h1, A.Wt2, A.s2, A.t2s, nullptr, A.out_before, A.out_after, 512, 80, 1);
}